// Round 6
// baseline (320.368 us; speedup 1.0000x reference)
//
#include <hip/hip_runtime.h>
#include <cstdint>

// ---------------------------------------------------------------------------
// NEO vision embeddings, MI355X (gfx950) — round 6: reg double-buffered pipe
//   conv:  pixf16[32768][608] (pad 588->608), B1 f16 [1024][608], B2 f16 perm
//   GEMM1: pe = rope(gelu(pixf16 @ B1^T + b1))          (256^2, BK=32)
//   GEMM2: out = gather(pe)[8192,4096] @ B2^T + b2      (256^2, BK=32)
// Per K32-iter: ds_read tile kt+1 -> NEXT reg set (no dep on MFMA), stage
// tile kt+3 (gload_lds), 32 MFMA on CUR reg set, then vmcnt(4)+lgkm(0)+bar.
// LDS-read latency is hidden by data-flow, not wave stagger.
// ---------------------------------------------------------------------------

using f16x8 = __attribute__((ext_vector_type(8))) _Float16;
using f32x4 = __attribute__((ext_vector_type(4))) float;

__device__ __forceinline__ void gload_lds16(const void* g, void* l) {
  __builtin_amdgcn_global_load_lds(
      reinterpret_cast<const __attribute__((address_space(1))) unsigned int*>(
          reinterpret_cast<uintptr_t>(g)),
      reinterpret_cast<__attribute__((address_space(3))) unsigned int*>(
          reinterpret_cast<uintptr_t>(l)),
      16, 0, 0);
}

__device__ __forceinline__ f16x8 ldsr(unsigned addr) {
  f16x8 r;
  asm volatile("ds_read_b128 %0, %1" : "=v"(r) : "v"(addr));
  return r;
}

// -------------------------- conversion kernels -----------------------------

__global__ void conv_b1_kernel(const float* __restrict__ w1,
                               _Float16* __restrict__ h) {
  int i = blockIdx.x * 256 + threadIdx.x;          // over 1024*608
  if (i >= 1024 * 608) return;
  int e = i / 608;
  int k = i - e * 608;
  float v = (k < 588) ? w1[(size_t)e * 588 + k] : 0.0f;
  h[i] = (_Float16)v;
}

__global__ void conv_b2_kernel(const float* __restrict__ w2,
                               _Float16* __restrict__ h) {
  int i = blockIdx.x * 256 + threadIdx.x;          // over 2048*4096
  int o   = i >> 12;
  int rem = i & 4095;
  int pq  = rem >> 10;
  int e   = rem & 1023;
  h[i] = (_Float16)w2[(size_t)o * 4096 + e * 4 + pq];
}

__global__ void conv_pix_kernel(const float* __restrict__ pix,
                                _Float16* __restrict__ h) {
  int i = blockIdx.x * 256 + threadIdx.x;          // over 32768*76
  if (i >= 32768 * 76) return;
  int n = i / 76;
  int g = i - n * 76;
  int k0 = g * 8;
  f16x8 v;
  if (k0 + 8 <= 588) {
    const float4 x0 = *(const float4*)(pix + (size_t)n * 588 + k0);
    const float4 x1 = *(const float4*)(pix + (size_t)n * 588 + k0 + 4);
    v[0] = (_Float16)x0.x; v[1] = (_Float16)x0.y;
    v[2] = (_Float16)x0.z; v[3] = (_Float16)x0.w;
    v[4] = (_Float16)x1.x; v[5] = (_Float16)x1.y;
    v[6] = (_Float16)x1.z; v[7] = (_Float16)x1.w;
  } else {
#pragma unroll
    for (int j = 0; j < 8; ++j) {
      int k = k0 + j;
      v[j] = (k < 588) ? (_Float16)pix[(size_t)n * 588 + k] : (_Float16)0.0f;
    }
  }
  *(f16x8*)(h + (size_t)n * 608 + k0) = v;
}

// ------------------------- shared schedule macros --------------------------

#define DR4 asm volatile("s_waitcnt vmcnt(4)" ::: "memory")
#define DR0 asm volatile("s_waitcnt vmcnt(0)" ::: "memory")
#define NODR ((void)0)

#define READ12(NA, NB, slotbase)                                           \
  _Pragma("unroll") for (int i = 0; i < 8; ++i)                            \
      NA[i] = ldsr((slotbase) + aoffs + (unsigned)(i * 1024));             \
  _Pragma("unroll") for (int j = 0; j < 4; ++j)                            \
      NB[j] = ldsr((slotbase) + boffs + (unsigned)(j * 1024));

#define MFMA32(CA, CB)                                                     \
  _Pragma("unroll") for (int i = 0; i < 8; ++i)                            \
      _Pragma("unroll") for (int j = 0; j < 4; ++j)                        \
          acc[i][j] = __builtin_amdgcn_mfma_f32_16x16x32_f16(              \
              CA[i], CB[j], acc[i][j], 0, 0, 0);

// Invariant at the barrier ending iter kt: tiles <= kt+2 landed in LDS;
// only tile kt+3's 4 loads outstanding.  Iter kt reads tile kt+1 into the
// NEXT reg set (guaranteed landed), stages tile kt+3, computes tile kt on
// the CUR reg set.  lgkm(0)+sched_barrier(0) fences the reads (rule 18);
// vmcnt BEFORE s_barrier makes the landing visible block-wide.
#define ITER(kt, CA, CB, NA, NB, DOREAD, DOST, STAGE_A, STAGE_B, DRAIN)    \
  {                                                                        \
    if (DOREAD) {                                                          \
      const unsigned nsb = base + ((unsigned)(((kt) + 1) & 3) << 15);      \
      READ12(NA, NB, nsb);                                                 \
    }                                                                      \
    if (DOST) { const int st = (kt) + 3; STAGE_A(st); STAGE_B(st); }       \
    __builtin_amdgcn_s_setprio(1);                                         \
    MFMA32(CA, CB);                                                        \
    __builtin_amdgcn_s_setprio(0);                                         \
    DRAIN;                                                                 \
    asm volatile("s_waitcnt lgkmcnt(0)" ::: "memory");                     \
    __builtin_amdgcn_sched_barrier(0);                                     \
    asm volatile("s_barrier" ::: "memory");                                \
  }

// ------------------------------- GEMM1 -------------------------------------

#define P_STAGE_A(s)                                                       \
  _Pragma("unroll") for (int c = 0; c < 2; ++c) {                          \
    const int m = tA + c * 16;                                             \
    gload_lds16(pixf + (size_t)m * 608 + (s) * 32 + gc,                    \
                &fr[(s) & 3][0][wave * 2 + c][0]);                         \
  }
#define P_STAGE_B(s)                                                       \
  _Pragma("unroll") for (int c = 0; c < 2; ++c) {                          \
    const int e = nB + c * 16;                                             \
    gload_lds16(b1w + (size_t)e * 608 + (s) * 32 + gc,                     \
                &fr[(s) & 3][1][wave * 2 + c][0]);                         \
  }

__global__ __launch_bounds__(512, 2) void patch_gemm8(
    const _Float16* __restrict__ pixf,
    const _Float16* __restrict__ b1w,
    const float* __restrict__ bias1,
    const float* __restrict__ cosx, const float* __restrict__ sinx,
    const float* __restrict__ cosy, const float* __restrict__ siny,
    _Float16* __restrict__ pe)
{
  __shared__ f16x8 fr[4][2][16][64];   // 128 KiB

  const int tid  = threadIdx.x;
  const int lane = tid & 63;
  const int wave = tid >> 6;
  const int wm = wave >> 2;            // 0..1
  const int wn = wave & 3;             // 0..3
  const int bm = blockIdx.x, bn = blockIdx.y;
  const int l15 = lane & 15;
  const int gc  = (lane >> 4) * 8;

  const unsigned base  = (unsigned)(uintptr_t)&fr[0][0][0][0];
  const unsigned aoffs = (unsigned)(wm * 8192 + lane * 16);
  const unsigned boffs = (unsigned)(16384 + wn * 4096 + lane * 16);

  const int bm256 = bm * 256;
  const int tA = bm256 + wave * 32 + l15;          // A stage row base
  const int nB = bn * 256 + wave * 32 + l15;       // B stage row base

  f32x4 acc[8][4] = {};
  f16x8 RA[8], RB[4], SA[8], SB[4];

  // prologue: stage tiles 0,1,2; ensure tiles 0,1 landed; load tile 0 frags
  P_STAGE_A(0); P_STAGE_B(0);
  P_STAGE_A(1); P_STAGE_B(1);
  P_STAGE_A(2); P_STAGE_B(2);
  DR4;
  asm volatile("s_barrier" ::: "memory");
  READ12(RA, RB, base);
  asm volatile("s_waitcnt lgkmcnt(0)" ::: "memory");
  __builtin_amdgcn_sched_barrier(0);

  for (int t = 0; t < 8; ++t) {
    const int kt = 2 * t;
    ITER(kt,     RA, RB, SA, SB, 1, 1, P_STAGE_A, P_STAGE_B, DR4);
    ITER(kt + 1, SA, SB, RA, RB, 1, 1, P_STAGE_A, P_STAGE_B, DR4);
  }
  ITER(16, RA, RB, SA, SB, 1, 0, P_STAGE_A, P_STAGE_B, DR0);
  ITER(17, SA, SB, RA, RB, 1, 0, P_STAGE_A, P_STAGE_B, NODR);
  ITER(18, RA, RB, SA, SB, 0, 0, P_STAGE_A, P_STAGE_B, NODR);

  // epilogue: bias + gelu + rope, f16 store
  const int md = (lane >> 4) * 4;
#pragma unroll
  for (int mf = 0; mf < 8; ++mf) {
#pragma unroll
    for (int r = 0; r < 4; ++r) {
      const int m = bm256 + wm * 128 + mf * 16 + md + r;
      const int pid  = m & 4095;
      const int posx = pid & 63;
      const int posy = (pid >> 6) & 63;
#pragma unroll
      for (int nf = 0; nf < 4; ++nf) {
        const int e = bn * 256 + wn * 64 + nf * 16 + l15;
        float v = acc[mf][nf][r] + bias1[e];
        v = 0.5f * v * (1.0f + erff(v * 0.70710678118654752f));
        const float pv = __shfl_xor(v, 1, 64);     // pair partner (e ^ 1)
        const int h2  = (e >= 512) ? 1 : 0;
        const int idx = (h2 ? (e - 512) : e) >> 1;
        const int pos = h2 ? posy : posx;
        const float cc = (h2 ? cosy : cosx)[pos * 256 + idx];
        const float ss = (h2 ? siny : sinx)[pos * 256 + idx];
        const float o = ((lane & 1) == 0) ? (v * cc - pv * ss)
                                          : (pv * ss + v * cc);
        pe[(size_t)m * 1024 + e] = (_Float16)o;
      }
    }
  }
}

// ------------------------------- GEMM2 -------------------------------------

#define D_STAGE_A(s)                                                       \
  {                                                                        \
    const int pq = (s) >> 5, p = pq >> 1, q = pq & 1;                      \
    const int e0 = ((s) & 31) << 5;                                        \
    _Pragma("unroll") for (int c = 0; c < 2; ++c) {                        \
      const int t_ = tA + c * 16;                                          \
      const int rr = t_ & 1023;                                            \
      const int prow =                                                     \
          (t_ >> 10) * 4096 + ((rr >> 5) * 2 + p) * 64 + (rr & 31) * 2 + q;\
      gload_lds16(pe + (size_t)prow * 1024 + e0 + gc,                      \
                  &fr[(s) & 3][0][wave * 2 + c][0]);                       \
    }                                                                      \
  }
#define D_STAGE_B(s)                                                       \
  _Pragma("unroll") for (int c = 0; c < 2; ++c) {                          \
    const int n = nB + c * 16;                                             \
    gload_lds16(b2w + (size_t)n * 4096 + (s) * 32 + gc,                    \
                &fr[(s) & 3][1][wave * 2 + c][0]);                         \
  }

__global__ __launch_bounds__(512, 2) void dense_gemm8(
    const _Float16* __restrict__ pe,
    const _Float16* __restrict__ b2w,
    const float* __restrict__ bias2, float* __restrict__ out)
{
  __shared__ f16x8 fr[4][2][16][64];   // 128 KiB

  const int tid  = threadIdx.x;
  const int lane = tid & 63;
  const int wave = tid >> 6;
  const int wm = wave >> 2;
  const int wn = wave & 3;
  const int bm = blockIdx.x, bn = blockIdx.y;
  const int l15 = lane & 15;
  const int gc  = (lane >> 4) * 8;

  const unsigned base  = (unsigned)(uintptr_t)&fr[0][0][0][0];
  const unsigned aoffs = (unsigned)(wm * 8192 + lane * 16);
  const unsigned boffs = (unsigned)(16384 + wn * 4096 + lane * 16);

  const int bm256 = bm * 256;
  const int tA = bm256 + wave * 32 + l15;
  const int nB = bn * 256 + wave * 32 + l15;

  f32x4 acc[8][4] = {};
  f16x8 RA[8], RB[4], SA[8], SB[4];

  D_STAGE_A(0); D_STAGE_B(0);
  D_STAGE_A(1); D_STAGE_B(1);
  D_STAGE_A(2); D_STAGE_B(2);
  DR4;
  asm volatile("s_barrier" ::: "memory");
  READ12(RA, RB, base);
  asm volatile("s_waitcnt lgkmcnt(0)" ::: "memory");
  __builtin_amdgcn_sched_barrier(0);

  for (int t = 0; t < 62; ++t) {
    const int kt = 2 * t;
    ITER(kt,     RA, RB, SA, SB, 1, 1, D_STAGE_A, D_STAGE_B, DR4);
    ITER(kt + 1, SA, SB, RA, RB, 1, 1, D_STAGE_A, D_STAGE_B, DR4);
  }
  ITER(124, RA, RB, SA, SB, 1, 1, D_STAGE_A, D_STAGE_B, DR4);
  ITER(125, SA, SB, RA, RB, 1, 0, D_STAGE_A, D_STAGE_B, DR0);
  ITER(126, RA, RB, SA, SB, 1, 0, D_STAGE_A, D_STAGE_B, NODR);
  ITER(127, SA, SB, RA, RB, 0, 0, D_STAGE_A, D_STAGE_B, NODR);

  // epilogue
  const int md = (lane >> 4) * 4;
  const int r0 = bm256 + wm * 128;
  const int c0 = bn * 256 + wn * 64;
#pragma unroll
  for (int nf = 0; nf < 4; ++nf) {
    const int o = c0 + nf * 16 + l15;
    const float bs = bias2[o];
#pragma unroll
    for (int mf = 0; mf < 8; ++mf) {
      const int t_ = r0 + mf * 16 + md;
#pragma unroll
      for (int r = 0; r < 4; ++r)
        out[(size_t)(t_ + r) * 2048 + o] = acc[mf][nf][r] + bs;
    }
  }
}

// ----------------------------- launcher ------------------------------------

extern "C" void kernel_launch(void* const* d_in, const int* in_sizes, int n_in,
                              void* d_out, int out_size, void* d_ws, size_t ws_size,
                              hipStream_t stream) {
  const float* pix  = (const float*)d_in[0];
  const float* w1   = (const float*)d_in[2];
  const float* b1   = (const float*)d_in[3];
  const float* w2   = (const float*)d_in[4];
  const float* b2   = (const float*)d_in[5];
  const float* cosx = (const float*)d_in[6];
  const float* sinx = (const float*)d_in[7];
  const float* cosy = (const float*)d_in[8];
  const float* siny = (const float*)d_in[9];
  float* out = (float*)d_out;

  _Float16* ws = (_Float16*)d_ws;
  const size_t PE_N  = (size_t)32768 * 1024;
  const size_t B1_N  = (size_t)1024 * 608;
  const size_t B2_N  = (size_t)2048 * 4096;
  _Float16* peb  = ws;
  _Float16* b1h  = peb + PE_N;
  _Float16* b2h  = b1h + B1_N;
  _Float16* pixf = b2h + B2_N;
  // total ws ~125 MB

  conv_b1_kernel<<<dim3(2432), dim3(256), 0, stream>>>(w1, b1h);
  conv_b2_kernel<<<dim3(32768), dim3(256), 0, stream>>>(w2, b2h);
  conv_pix_kernel<<<dim3(9728), dim3(256), 0, stream>>>(pix, pixf);
  patch_gemm8<<<dim3(128, 4), dim3(512), 0, stream>>>(
      pixf, b1h, b1, cosx, sinx, cosy, siny, peb);
  dense_gemm8<<<dim3(32, 8), dim3(512), 0, stream>>>(
      peb, b2h, b2, out);
}

// Round 8
// 303.090 us; speedup vs baseline: 1.0570x; 1.0570x over previous
//
#include <hip/hip_runtime.h>
#include <cstdint>

// ---------------------------------------------------------------------------
// NEO vision embeddings, MI355X (gfx950) — round 8: r7 + corrected vmcnt drains
//   conv:  pixf16[32768][640] (pad 588->640), B1 f16 [1024][640], B2 f16 perm
//   GEMM1: pe = rope(gelu(pixf16 @ B1^T + b1))          (256^2, BK=64)
//   GEMM2: out = gather(pe)[8192,4096] @ B2^T + b2      (256^2, BK=64)
// LDS: [2 dbuf][4 halves: A0,A1,B0,B1][128 rows][128 B], XOR-swizzled chunks
// (slot = gcol ^ (row&7)) via pre-swizzled global source. Each gload_lds
// covers 8 full 128-B rows (coalesced). 4 phases per K64-tile.
// Drain proof (per-wave queue, steady iter s issues A0,A1 of s+1 / B0,B1 of
// s+2, 2 loads each): ph3 must retire BOTH A pairs before the barrier ->
// vmcnt(4); ph1/ph2 vmcnt(6) retire the B pairs one iter early. Tail: last
// staging iter ends vmcnt(0). (r7's V6/V2 left A1 in flight -> race.)
// ---------------------------------------------------------------------------

using f16x8 = __attribute__((ext_vector_type(8))) _Float16;
using f32x4 = __attribute__((ext_vector_type(4))) float;

__device__ __forceinline__ void gload_lds16(const void* g, void* l) {
  __builtin_amdgcn_global_load_lds(
      reinterpret_cast<const __attribute__((address_space(1))) unsigned int*>(
          reinterpret_cast<uintptr_t>(g)),
      reinterpret_cast<__attribute__((address_space(3))) unsigned int*>(
          reinterpret_cast<uintptr_t>(l)),
      16, 0, 0);
}

__device__ __forceinline__ f16x8 ldsr(unsigned addr) {
  f16x8 r;
  asm volatile("ds_read_b128 %0, %1" : "=v"(r) : "v"(addr));
  return r;
}

// -------------------------- conversion kernels -----------------------------

#define KP 640   // padded K for GEMM1

__global__ void conv_b1_kernel(const float* __restrict__ w1,
                               _Float16* __restrict__ h) {
  int i = blockIdx.x * 256 + threadIdx.x;          // over 1024*KP
  if (i >= 1024 * KP) return;
  int e = i / KP;
  int k = i - e * KP;
  float v = (k < 588) ? w1[(size_t)e * 588 + k] : 0.0f;
  h[i] = (_Float16)v;
}

__global__ void conv_b2_kernel(const float* __restrict__ w2,
                               _Float16* __restrict__ h) {
  int i = blockIdx.x * 256 + threadIdx.x;          // over 2048*4096
  int o   = i >> 12;
  int rem = i & 4095;
  int pq  = rem >> 10;
  int e   = rem & 1023;
  h[i] = (_Float16)w2[(size_t)o * 4096 + e * 4 + pq];
}

__global__ void conv_pix_kernel(const float* __restrict__ pix,
                                _Float16* __restrict__ h) {
  int i = blockIdx.x * 256 + threadIdx.x;          // over 32768*(KP/8)
  if (i >= 32768 * (KP / 8)) return;
  int n = i / (KP / 8);
  int g = i - n * (KP / 8);
  int k0 = g * 8;
  f16x8 v;
  if (k0 + 8 <= 588) {
    const float4 x0 = *(const float4*)(pix + (size_t)n * 588 + k0);
    const float4 x1 = *(const float4*)(pix + (size_t)n * 588 + k0 + 4);
    v[0] = (_Float16)x0.x; v[1] = (_Float16)x0.y;
    v[2] = (_Float16)x0.z; v[3] = (_Float16)x0.w;
    v[4] = (_Float16)x1.x; v[5] = (_Float16)x1.y;
    v[6] = (_Float16)x1.z; v[7] = (_Float16)x1.w;
  } else {
#pragma unroll
    for (int j = 0; j < 8; ++j) {
      int k = k0 + j;
      v[j] = (k < 588) ? (_Float16)pix[(size_t)n * 588 + k] : (_Float16)0.0f;
    }
  }
  *(f16x8*)(h + (size_t)n * KP + k0) = v;
}

// ------------------------- schedule primitives -----------------------------

#define BAR   asm volatile("s_barrier" ::: "memory")
#define LGKM0 do { asm volatile("s_waitcnt lgkmcnt(0)" ::: "memory");         \
                   __builtin_amdgcn_sched_barrier(0); } while (0)
#define V6  asm volatile("s_waitcnt vmcnt(6)" ::: "memory")
#define V4  asm volatile("s_waitcnt vmcnt(4)" ::: "memory")
#define V0  asm volatile("s_waitcnt vmcnt(0)" ::: "memory")
#define VN  ((void)0)

#define MM16(I0, J0, AV, BV)                                                  \
  _Pragma("unroll") for (int i_ = 0; i_ < 4; ++i_)                            \
  _Pragma("unroll") for (int j_ = 0; j_ < 2; ++j_)                            \
  _Pragma("unroll") for (int ks_ = 0; ks_ < 2; ++ks_)                         \
      acc[(I0) + i_][(J0) + j_] = __builtin_amdgcn_mfma_f32_16x16x32_f16(     \
          AV[i_][ks_], BV[j_][ks_], acc[(I0) + i_][(J0) + j_], 0, 0, 0);

// 4 phases per K64-tile. Reads: ph0 a(lo)+b0, ph1 b1, ph2 a(hi), ph3 none.
// Stages: ph0 A0(s+1), ph1 A1(s+1), ph2 B0(s+2), ph3 B1(s+2).
// Drains (steady): V6, V6, V6, V4 — see proof at top.
#define TILE_ITER(s, DOA, DOB, STGA, STGB, DRA, DRB, DRC, DRD)                \
  {                                                                           \
    const unsigned dbase = base + ((unsigned)((s) & 1) << 16);                \
    f16x8 av[4][2], vb0[2][2], vb1[2][2];                                     \
    /* ---- phase 0 ---- */                                                   \
    _Pragma("unroll") for (int i = 0; i < 4; ++i) {                           \
      av[i][0] = ldsr(dbase + aoffs + (unsigned)(i * 2048) + soff0);          \
      av[i][1] = ldsr(dbase + aoffs + (unsigned)(i * 2048) + soff1);          \
    }                                                                         \
    _Pragma("unroll") for (int j = 0; j < 2; ++j) {                           \
      vb0[j][0] = ldsr(dbase + boffs + (unsigned)(j * 2048) + soff0);         \
      vb0[j][1] = ldsr(dbase + boffs + (unsigned)(j * 2048) + soff1);         \
    }                                                                         \
    if (DOA) STGA(0, (s) + 1);                                                \
    BAR; LGKM0;                                                               \
    __builtin_amdgcn_s_setprio(1);                                            \
    MM16(0, 0, av, vb0);                                                      \
    __builtin_amdgcn_s_setprio(0);                                            \
    DRA; BAR;                                                                 \
    /* ---- phase 1 ---- */                                                   \
    _Pragma("unroll") for (int j = 0; j < 2; ++j) {                           \
      vb1[j][0] = ldsr(dbase + boffs + (unsigned)((2 + j) * 2048) + soff0);   \
      vb1[j][1] = ldsr(dbase + boffs + (unsigned)((2 + j) * 2048) + soff1);   \
    }                                                                         \
    if (DOA) STGA(1, (s) + 1);                                                \
    BAR; LGKM0;                                                               \
    __builtin_amdgcn_s_setprio(1);                                            \
    MM16(0, 2, av, vb1);                                                      \
    __builtin_amdgcn_s_setprio(0);                                            \
    DRB; BAR;                                                                 \
    /* ---- phase 2 ---- */                                                   \
    _Pragma("unroll") for (int i = 0; i < 4; ++i) {                           \
      av[i][0] = ldsr(dbase + aoffs + (unsigned)((4 + i) * 2048) + soff0);    \
      av[i][1] = ldsr(dbase + aoffs + (unsigned)((4 + i) * 2048) + soff1);    \
    }                                                                         \
    if (DOB) STGB(0, (s) + 2);                                                \
    BAR; LGKM0;                                                               \
    __builtin_amdgcn_s_setprio(1);                                            \
    MM16(4, 2, av, vb1);                                                      \
    __builtin_amdgcn_s_setprio(0);                                            \
    DRC; BAR;                                                                 \
    /* ---- phase 3 ---- */                                                   \
    if (DOB) STGB(1, (s) + 2);                                                \
    BAR;                                                                      \
    __builtin_amdgcn_s_setprio(1);                                            \
    MM16(4, 0, av, vb0);                                                      \
    __builtin_amdgcn_s_setprio(0);                                            \
    DRD; BAR;                                                                 \
  }

// ------------------------------- GEMM1 -------------------------------------
// half h staged: 1024 chunks of 16B; wave instr = 8 rows x 128 B (coalesced).
// LDS(row, slot) = global chunk (row, slot ^ (row&7)).

#define P_STGA(h, s)                                                          \
  _Pragma("unroll") for (int u = 0; u < 2; ++u) {                             \
    const int ibase = wave * 64 + u * 512;                                    \
    const int i = ibase + lane;                                               \
    const int row = i >> 3;                                                   \
    const int m = bm256 + (h) * 128 + row;                                    \
    const int gcol = (i & 7) ^ (row & 7);                                     \
    gload_lds16(pixf + (size_t)m * KP + (s) * 64 + gcol * 8,                  \
                (char*)lds + (((s) & 1) * 65536 + (h) * 16384 + ibase * 16)); \
  }
#define P_STGB(h, s)                                                          \
  _Pragma("unroll") for (int u = 0; u < 2; ++u) {                             \
    const int ibase = wave * 64 + u * 512;                                    \
    const int i = ibase + lane;                                               \
    const int row = i >> 3;                                                   \
    const int e = bn * 256 + (h) * 128 + row;                                 \
    const int gcol = (i & 7) ^ (row & 7);                                     \
    gload_lds16(b1w + (size_t)e * KP + (s) * 64 + gcol * 8,                   \
                (char*)lds + (((s) & 1) * 65536 + (2 + (h)) * 16384 +         \
                              ibase * 16));                                   \
  }

__global__ __launch_bounds__(512, 2) void patch_gemm8(
    const _Float16* __restrict__ pixf,
    const _Float16* __restrict__ b1w,
    const float* __restrict__ bias1,
    const float* __restrict__ cosx, const float* __restrict__ sinx,
    const float* __restrict__ cosy, const float* __restrict__ siny,
    _Float16* __restrict__ pe)
{
  __shared__ _Float16 lds[2][4][128][64];   // 128 KiB

  const int tid  = threadIdx.x;
  const int lane = tid & 63;
  const int wave = tid >> 6;
  const int wm = wave >> 2;            // 0..1 (M half)
  const int wn = wave & 3;             // 0..3 (N quarter)
  const int bm = blockIdx.x, bn = blockIdx.y;
  const int l15 = lane & 15;
  const int g   = lane >> 4;
  const int s7  = l15 & 7;

  const unsigned base  = (unsigned)(uintptr_t)&lds[0][0][0][0];
  const unsigned aoffs = (unsigned)(wm * 16384 + l15 * 128);
  const unsigned boffs = (unsigned)(32768 + (wn >> 1) * 16384 +
                                    (wn & 1) * 8192 + l15 * 128);
  const unsigned soff0 = (unsigned)(((0 + g) ^ s7) * 16);
  const unsigned soff1 = (unsigned)(((4 + g) ^ s7) * 16);

  const int bm256 = bm * 256;

  f32x4 acc[8][4] = {};

  // prologue: tile0 all 4 halves + tile1 B halves
  P_STGA(0, 0); P_STGA(1, 0); P_STGB(0, 0); P_STGB(1, 0);
  P_STGB(0, 1); P_STGB(1, 1);
  V0; BAR;

  for (int kt = 0; kt < 8; ++kt)
    TILE_ITER(kt, 1, 1, P_STGA, P_STGB, V6, V6, V6, V4);
  TILE_ITER(8, 1, 0, P_STGA, P_STGB, V6, V6, V6, V0);
  TILE_ITER(9, 0, 0, P_STGA, P_STGB, VN, VN, VN, VN);

  // epilogue: bias + gelu + rope, f16 store
  const int md = (lane >> 4) * 4;
#pragma unroll
  for (int mf = 0; mf < 8; ++mf) {
#pragma unroll
    for (int r = 0; r < 4; ++r) {
      const int m = bm256 + wm * 128 + mf * 16 + md + r;
      const int pid  = m & 4095;
      const int posx = pid & 63;
      const int posy = (pid >> 6) & 63;
#pragma unroll
      for (int nf = 0; nf < 4; ++nf) {
        const int e = bn * 256 + wn * 64 + nf * 16 + l15;
        float v = acc[mf][nf][r] + bias1[e];
        v = 0.5f * v * (1.0f + erff(v * 0.70710678118654752f));
        const float pv = __shfl_xor(v, 1, 64);     // pair partner (e ^ 1)
        const int h2  = (e >= 512) ? 1 : 0;
        const int idx = (h2 ? (e - 512) : e) >> 1;
        const int pos = h2 ? posy : posx;
        const float cc = (h2 ? cosy : cosx)[pos * 256 + idx];
        const float ss = (h2 ? siny : sinx)[pos * 256 + idx];
        const float o = ((lane & 1) == 0) ? (v * cc - pv * ss)
                                          : (pv * ss + v * cc);
        pe[(size_t)m * 1024 + e] = (_Float16)o;
      }
    }
  }
}

// ------------------------------- GEMM2 -------------------------------------

#define D_STGA(h, s)                                                          \
  {                                                                           \
    const int pq = (s) >> 4, p = pq >> 1, q = pq & 1;                         \
    const int e0 = ((s) & 15) << 6;                                           \
    _Pragma("unroll") for (int u = 0; u < 2; ++u) {                           \
      const int ibase = wave * 64 + u * 512;                                  \
      const int i = ibase + lane;                                             \
      const int row = i >> 3;                                                 \
      const int t_ = bm256 + (h) * 128 + row;                                 \
      const int rr = t_ & 1023;                                               \
      const int prow =                                                        \
          (t_ >> 10) * 4096 + ((rr >> 5) * 2 + p) * 64 + (rr & 31) * 2 + q;   \
      const int gcol = (i & 7) ^ (row & 7);                                   \
      gload_lds16(pe + (size_t)prow * 1024 + e0 + gcol * 8,                   \
                  (char*)lds + (((s) & 1) * 65536 + (h) * 16384 +             \
                                ibase * 16));                                 \
    }                                                                         \
  }
#define D_STGB(h, s)                                                          \
  _Pragma("unroll") for (int u = 0; u < 2; ++u) {                             \
    const int ibase = wave * 64 + u * 512;                                    \
    const int i = ibase + lane;                                               \
    const int row = i >> 3;                                                   \
    const int n = bn * 256 + (h) * 128 + row;                                 \
    const int gcol = (i & 7) ^ (row & 7);                                     \
    gload_lds16(b2w + (size_t)n * 4096 + (s) * 64 + gcol * 8,                 \
                (char*)lds + (((s) & 1) * 65536 + (2 + (h)) * 16384 +         \
                              ibase * 16));                                   \
  }

__global__ __launch_bounds__(512, 2) void dense_gemm8(
    const _Float16* __restrict__ pe,
    const _Float16* __restrict__ b2w,
    const float* __restrict__ bias2, float* __restrict__ out)
{
  __shared__ _Float16 lds[2][4][128][64];   // 128 KiB

  const int tid  = threadIdx.x;
  const int lane = tid & 63;
  const int wave = tid >> 6;
  const int wm = wave >> 2;
  const int wn = wave & 3;
  // bijective XCD swizzle over 256 blocks (256 % 8 == 0): each XCD owns one
  // bn column -> B-panel (2 MB) L2-resident per XCD
  const int f   = blockIdx.x;
  const int swz = (f & 7) * 32 + (f >> 3);
  const int bm  = swz & 31;
  const int bn  = swz >> 5;
  const int l15 = lane & 15;
  const int g   = lane >> 4;
  const int s7  = l15 & 7;

  const unsigned base  = (unsigned)(uintptr_t)&lds[0][0][0][0];
  const unsigned aoffs = (unsigned)(wm * 16384 + l15 * 128);
  const unsigned boffs = (unsigned)(32768 + (wn >> 1) * 16384 +
                                    (wn & 1) * 8192 + l15 * 128);
  const unsigned soff0 = (unsigned)(((0 + g) ^ s7) * 16);
  const unsigned soff1 = (unsigned)(((4 + g) ^ s7) * 16);

  const int bm256 = bm * 256;

  f32x4 acc[8][4] = {};

  D_STGA(0, 0); D_STGA(1, 0); D_STGB(0, 0); D_STGB(1, 0);
  D_STGB(0, 1); D_STGB(1, 1);
  V0; BAR;

  for (int kt = 0; kt < 62; ++kt)
    TILE_ITER(kt, 1, 1, D_STGA, D_STGB, V6, V6, V6, V4);
  TILE_ITER(62, 1, 0, D_STGA, D_STGB, V6, V6, V6, V0);
  TILE_ITER(63, 0, 0, D_STGA, D_STGB, VN, VN, VN, VN);

  // epilogue
  const int md = (lane >> 4) * 4;
  const int r0 = bm256 + wm * 128;
  const int c0 = bn * 256 + wn * 64;
#pragma unroll
  for (int nf = 0; nf < 4; ++nf) {
    const int o = c0 + nf * 16 + l15;
    const float bs = bias2[o];
#pragma unroll
    for (int mf = 0; mf < 8; ++mf) {
      const int t_ = r0 + mf * 16 + md;
#pragma unroll
      for (int r = 0; r < 4; ++r)
        out[(size_t)(t_ + r) * 2048 + o] = acc[mf][nf][r] + bs;
    }
  }
}

// ----------------------------- launcher ------------------------------------

extern "C" void kernel_launch(void* const* d_in, const int* in_sizes, int n_in,
                              void* d_out, int out_size, void* d_ws, size_t ws_size,
                              hipStream_t stream) {
  const float* pix  = (const float*)d_in[0];
  const float* w1   = (const float*)d_in[2];
  const float* b1   = (const float*)d_in[3];
  const float* w2   = (const float*)d_in[4];
  const float* b2   = (const float*)d_in[5];
  const float* cosx = (const float*)d_in[6];
  const float* sinx = (const float*)d_in[7];
  const float* cosy = (const float*)d_in[8];
  const float* siny = (const float*)d_in[9];
  float* out = (float*)d_out;

  _Float16* ws = (_Float16*)d_ws;
  const size_t PE_N  = (size_t)32768 * 1024;
  const size_t B1_N  = (size_t)1024 * KP;
  const size_t B2_N  = (size_t)2048 * 4096;
  _Float16* peb  = ws;
  _Float16* b1h  = peb + PE_N;
  _Float16* b2h  = b1h + B1_N;
  _Float16* pixf = b2h + B2_N;
  // total ws ~128 MB

  conv_b1_kernel<<<dim3((1024 * KP + 255) / 256), dim3(256), 0, stream>>>(w1, b1h);
  conv_b2_kernel<<<dim3(32768), dim3(256), 0, stream>>>(w2, b2h);
  conv_pix_kernel<<<dim3((32768 * (KP / 8) + 255) / 256), dim3(256), 0, stream>>>(pix, pixf);
  patch_gemm8<<<dim3(128, 4), dim3(512), 0, stream>>>(
      pixf, b1h, b1, cosx, sinx, cosy, siny, peb);
  dense_gemm8<<<dim3(256), dim3(512), 0, stream>>>(
      peb, b2h, b2, out);
}

// Round 9
// 290.759 us; speedup vs baseline: 1.1018x; 1.0424x over previous
//
#include <hip/hip_runtime.h>
#include <cstdint>

// ---------------------------------------------------------------------------
// NEO vision embeddings, MI355X (gfx950) — round 9: 1-barrier/tile, compiler-
// scheduled reads, pre-merged PE.
//   conv:  pixf16[32768][640], B1 f16 [1024][640], B2 f16 perm [2048][4096]
//   GEMM1: peM = merge(rope(gelu(pixf @ B1^T + b1)))    (256^2, BK=64)
//   GEMM2: out = peM[8192,4096] @ B2^T + b2             (256^2, BK=64)
// Per K64-tile: stage A(s+1)+B(s+1) -> slot (s+1)&1 (8 gload/wave, coalesced
// 8x128B rows, XOR-swizzled source); 24 plain ds_read_b128 + 64 MFMA
// (compiler interleaves with partial lgkm waits); lgkm0 + vmcnt0 (both ~free,
// loads had a full tile of cover) + ONE s_barrier.
// Hazards: in-flight writes target slot (s+1)&1, reads target s&1 (disjoint);
// next tile's writes to s&1 are issued only after this tile's lgkm0+barrier.
// ---------------------------------------------------------------------------

using f16x8 = __attribute__((ext_vector_type(8))) _Float16;
using f32x4 = __attribute__((ext_vector_type(4))) float;

__device__ __forceinline__ void gload_lds16(const void* g, void* l) {
  __builtin_amdgcn_global_load_lds(
      reinterpret_cast<const __attribute__((address_space(1))) unsigned int*>(
          reinterpret_cast<uintptr_t>(g)),
      reinterpret_cast<__attribute__((address_space(3))) unsigned int*>(
          reinterpret_cast<uintptr_t>(l)),
      16, 0, 0);
}

#define BAR   asm volatile("s_barrier" ::: "memory")
#define LGKM0 asm volatile("s_waitcnt lgkmcnt(0)" ::: "memory")
#define VM0   asm volatile("s_waitcnt vmcnt(0)" ::: "memory")

#define KP 640   // padded K for GEMM1 (588 -> 640 = 10 x 64)

// -------------------------- conversion kernels -----------------------------

__global__ void conv_b1_kernel(const float* __restrict__ w1,
                               _Float16* __restrict__ h) {
  int i = blockIdx.x * 256 + threadIdx.x;          // over 1024*KP
  if (i >= 1024 * KP) return;
  int e = i / KP;
  int k = i - e * KP;
  float v = (k < 588) ? w1[(size_t)e * 588 + k] : 0.0f;
  h[i] = (_Float16)v;
}

__global__ void conv_b2_kernel(const float* __restrict__ w2,
                               _Float16* __restrict__ h) {
  int i = blockIdx.x * 256 + threadIdx.x;          // over 2048*4096
  int o   = i >> 12;
  int rem = i & 4095;
  int pq  = rem >> 10;
  int e   = rem & 1023;
  h[i] = (_Float16)w2[(size_t)o * 4096 + e * 4 + pq];
}

__global__ void conv_pix_kernel(const float* __restrict__ pix,
                                _Float16* __restrict__ h) {
  int i = blockIdx.x * 256 + threadIdx.x;          // over 32768*(KP/8)
  if (i >= 32768 * (KP / 8)) return;
  int n = i / (KP / 8);
  int g = i - n * (KP / 8);
  int k0 = g * 8;
  f16x8 v;
  if (k0 + 8 <= 588) {
    const float4 x0 = *(const float4*)(pix + (size_t)n * 588 + k0);
    const float4 x1 = *(const float4*)(pix + (size_t)n * 588 + k0 + 4);
    v[0] = (_Float16)x0.x; v[1] = (_Float16)x0.y;
    v[2] = (_Float16)x0.z; v[3] = (_Float16)x0.w;
    v[4] = (_Float16)x1.x; v[5] = (_Float16)x1.y;
    v[6] = (_Float16)x1.z; v[7] = (_Float16)x1.w;
  } else {
#pragma unroll
    for (int j = 0; j < 8; ++j) {
      int k = k0 + j;
      v[j] = (k < 588) ? (_Float16)pix[(size_t)n * 588 + k] : (_Float16)0.0f;
    }
  }
  *(f16x8*)(h + (size_t)n * KP + k0) = v;
}

// ------------------------- shared GEMM body macros -------------------------
// LDS slot layout: [A rows 0-255][B rows 0-255], row-major 128 B/row, chunk
// slot within row = gcol ^ (row&7) (inverse-swizzled at the global source).

#define MFMA16(I0, J0, AV, BV)                                                \
  _Pragma("unroll") for (int i_ = 0; i_ < 4; ++i_)                            \
  _Pragma("unroll") for (int j_ = 0; j_ < 2; ++j_)                            \
  _Pragma("unroll") for (int k_ = 0; k_ < 2; ++k_)                            \
      acc[(I0) + i_][(J0) + j_] = __builtin_amdgcn_mfma_f32_16x16x32_f16(     \
          AV[i_][k_], BV[j_][k_], acc[(I0) + i_][(J0) + j_], 0, 0, 0);

#define TILE_BODY(sb)                                                         \
  {                                                                           \
    f16x8 a0[4][2], a1[4][2], vb0[2][2], vb1[2][2];                           \
    _Pragma("unroll") for (int i = 0; i < 4; ++i) {                           \
      a0[i][0] = *(const f16x8*)(lbase + (sb) + aoff + i * 2048 + so0);       \
      a0[i][1] = *(const f16x8*)(lbase + (sb) + aoff + i * 2048 + so1);       \
    }                                                                         \
    _Pragma("unroll") for (int j = 0; j < 2; ++j) {                           \
      vb0[j][0] = *(const f16x8*)(lbase + (sb) + boff + j * 2048 + so0);      \
      vb0[j][1] = *(const f16x8*)(lbase + (sb) + boff + j * 2048 + so1);      \
    }                                                                         \
    MFMA16(0, 0, a0, vb0);                                                    \
    _Pragma("unroll") for (int j = 0; j < 2; ++j) {                           \
      vb1[j][0] = *(const f16x8*)(lbase + (sb) + boff + (2+j) * 2048 + so0);  \
      vb1[j][1] = *(const f16x8*)(lbase + (sb) + boff + (2+j) * 2048 + so1);  \
    }                                                                         \
    MFMA16(0, 2, a0, vb1);                                                    \
    _Pragma("unroll") for (int i = 0; i < 4; ++i) {                           \
      a1[i][0] = *(const f16x8*)(lbase + (sb) + aoff + (4+i) * 2048 + so0);   \
      a1[i][1] = *(const f16x8*)(lbase + (sb) + aoff + (4+i) * 2048 + so1);   \
    }                                                                         \
    MFMA16(4, 2, a1, vb1);                                                    \
    MFMA16(4, 0, a1, vb0);                                                    \
  }

// ------------------------------- GEMM1 -------------------------------------

__global__ __launch_bounds__(512, 2) void patch_gemm9(
    const _Float16* __restrict__ pixf,
    const _Float16* __restrict__ b1w,
    const float* __restrict__ bias1,
    const float* __restrict__ cosx, const float* __restrict__ sinx,
    const float* __restrict__ cosy, const float* __restrict__ siny,
    _Float16* __restrict__ peM)
{
  __shared__ _Float16 lds[2][2][256][64];   // 128 KiB

  const int tid  = threadIdx.x;
  const int lane = tid & 63;
  const int wave = tid >> 6;
  const int wm = wave >> 2, wn = wave & 3;
  const int bm = blockIdx.x, bn = blockIdx.y;
  const int l15 = lane & 15;
  const int g   = lane >> 4;
  const int s7  = l15 & 7;

  const char* lbase = (const char*)lds;
  char*       lw    = (char*)lds;
  const unsigned aoff = (unsigned)(wm * 16384 + l15 * 128);
  const unsigned boff = (unsigned)(32768 + wn * 8192 + l15 * 128);
  const unsigned so0  = (unsigned)(((0 + g) ^ s7) * 16);
  const unsigned so1  = (unsigned)(((4 + g) ^ s7) * 16);

  const int bm256 = bm * 256, bn256 = bn * 256;
  const int srow = (wave * 4) * 8 + (lane >> 3);      // staging row base
  const int sgc  = (lane & 7) ^ (srow & 7);           // swizzled chunk (u=0)

  auto STAGE = [&](int s) {
    char* slot = lw + ((size_t)(s & 1) << 16);
    const int c0 = s * 64;
#pragma unroll
    for (int u = 0; u < 4; ++u) {
      const int row  = srow + u * 8;
      const int gcol = (lane & 7) ^ (row & 7);
      gload_lds16(pixf + (size_t)(bm256 + row) * KP + c0 + gcol * 8,
                  slot + (wave * 4 + u) * 1024);
      gload_lds16(b1w + (size_t)(bn256 + row) * KP + c0 + gcol * 8,
                  slot + 32768 + (wave * 4 + u) * 1024);
    }
  };
  (void)sgc;

  f32x4 acc[8][4] = {};

  STAGE(0); VM0; BAR;
#pragma unroll 2
  for (int s = 0; s < 10; ++s) {
    if (s + 1 < 10) STAGE(s + 1);
    const unsigned sb = (unsigned)((s & 1) << 16);
    __builtin_amdgcn_s_setprio(1);
    TILE_BODY(sb);
    __builtin_amdgcn_s_setprio(0);
    LGKM0; VM0; BAR;
  }

  // epilogue: bias + gelu + rope, write PE in MERGED layout [8192][4096]
  const int md = (lane >> 4) * 4;
#pragma unroll
  for (int mf = 0; mf < 8; ++mf) {
#pragma unroll
    for (int r = 0; r < 4; ++r) {
      const int m = bm256 + wm * 128 + mf * 16 + md + r;
      const int pid  = m & 4095;
      const int yy = pid >> 6, xx = pid & 63;
      const int t  = (m >> 12) * 1024 + (yy >> 1) * 32 + (xx >> 1);
      const int pq = (yy & 1) * 2 + (xx & 1);
      _Float16* dst = peM + (size_t)t * 4096 + pq * 1024;
#pragma unroll
      for (int nf = 0; nf < 4; ++nf) {
        const int e = bn256 + wn * 64 + nf * 16 + l15;
        float v = acc[mf][nf][r] + bias1[e];
        v = 0.5f * v * (1.0f + erff(v * 0.70710678118654752f));
        const float pv = __shfl_xor(v, 1, 64);     // pair partner (e ^ 1)
        const int h2  = (e >= 512) ? 1 : 0;
        const int idx = (h2 ? (e - 512) : e) >> 1;
        const int pos = h2 ? ((pid >> 6) & 63) : (pid & 63);
        const float cc = (h2 ? cosy : cosx)[pos * 256 + idx];
        const float ss = (h2 ? siny : sinx)[pos * 256 + idx];
        const float o = ((lane & 1) == 0) ? (v * cc - pv * ss)
                                          : (pv * ss + v * cc);
        dst[e] = (_Float16)o;
      }
    }
  }
}

// ------------------------------- GEMM2 -------------------------------------

__global__ __launch_bounds__(512, 2) void dense_gemm9(
    const _Float16* __restrict__ aM,    // [8192][4096] merged pe
    const _Float16* __restrict__ bM,    // [2048][4096] permuted w2
    const float* __restrict__ bias2, float* __restrict__ out)
{
  __shared__ _Float16 lds[2][2][256][64];   // 128 KiB

  const int tid  = threadIdx.x;
  const int lane = tid & 63;
  const int wave = tid >> 6;
  const int wm = wave >> 2, wn = wave & 3;
  const int bm = blockIdx.x, bn = blockIdx.y;
  const int l15 = lane & 15;
  const int g   = lane >> 4;
  const int s7  = l15 & 7;

  const char* lbase = (const char*)lds;
  char*       lw    = (char*)lds;
  const unsigned aoff = (unsigned)(wm * 16384 + l15 * 128);
  const unsigned boff = (unsigned)(32768 + wn * 8192 + l15 * 128);
  const unsigned so0  = (unsigned)(((0 + g) ^ s7) * 16);
  const unsigned so1  = (unsigned)(((4 + g) ^ s7) * 16);

  const int bm256 = bm * 256, bn256 = bn * 256;
  const int srow = (wave * 4) * 8 + (lane >> 3);

  auto STAGE = [&](int s) {
    char* slot = lw + ((size_t)(s & 1) << 16);
    const int c0 = s * 64;
#pragma unroll
    for (int u = 0; u < 4; ++u) {
      const int row  = srow + u * 8;
      const int gcol = (lane & 7) ^ (row & 7);
      gload_lds16(aM + (size_t)(bm256 + row) * 4096 + c0 + gcol * 8,
                  slot + (wave * 4 + u) * 1024);
      gload_lds16(bM + (size_t)(bn256 + row) * 4096 + c0 + gcol * 8,
                  slot + 32768 + (wave * 4 + u) * 1024);
    }
  };

  f32x4 acc[8][4] = {};

  STAGE(0); VM0; BAR;
#pragma unroll 2
  for (int s = 0; s < 64; ++s) {
    if (s + 1 < 64) STAGE(s + 1);
    const unsigned sb = (unsigned)((s & 1) << 16);
    __builtin_amdgcn_s_setprio(1);
    TILE_BODY(sb);
    __builtin_amdgcn_s_setprio(0);
    LGKM0; VM0; BAR;
  }

  // epilogue
  const int md = (lane >> 4) * 4;
  const int r0 = bm256 + wm * 128;
  const int c0 = bn256 + wn * 64;
#pragma unroll
  for (int nf = 0; nf < 4; ++nf) {
    const int o = c0 + nf * 16 + l15;
    const float bs = bias2[o];
#pragma unroll
    for (int mf = 0; mf < 8; ++mf) {
      const int t_ = r0 + mf * 16 + md;
#pragma unroll
      for (int r = 0; r < 4; ++r)
        out[(size_t)(t_ + r) * 2048 + o] = acc[mf][nf][r] + bs;
    }
  }
}

// ----------------------------- launcher ------------------------------------

extern "C" void kernel_launch(void* const* d_in, const int* in_sizes, int n_in,
                              void* d_out, int out_size, void* d_ws, size_t ws_size,
                              hipStream_t stream) {
  const float* pix  = (const float*)d_in[0];
  const float* w1   = (const float*)d_in[2];
  const float* b1   = (const float*)d_in[3];
  const float* w2   = (const float*)d_in[4];
  const float* b2   = (const float*)d_in[5];
  const float* cosx = (const float*)d_in[6];
  const float* sinx = (const float*)d_in[7];
  const float* cosy = (const float*)d_in[8];
  const float* siny = (const float*)d_in[9];
  float* out = (float*)d_out;

  _Float16* ws = (_Float16*)d_ws;
  const size_t PE_N  = (size_t)8192 * 4096;
  const size_t B1_N  = (size_t)1024 * KP;
  const size_t B2_N  = (size_t)2048 * 4096;
  _Float16* peM  = ws;
  _Float16* b1h  = peM + PE_N;
  _Float16* b2h  = b1h + B1_N;
  _Float16* pixf = b2h + B2_N;
  // total ws ~128 MB

  conv_b1_kernel<<<dim3((1024 * KP + 255) / 256), dim3(256), 0, stream>>>(w1, b1h);
  conv_b2_kernel<<<dim3(32768), dim3(256), 0, stream>>>(w2, b2h);
  conv_pix_kernel<<<dim3((32768 * (KP / 8) + 255) / 256), dim3(256), 0, stream>>>(pix, pixf);
  patch_gemm9<<<dim3(128, 4), dim3(512), 0, stream>>>(
      pixf, b1h, b1, cosx, sinx, cosy, siny, peM);
  dense_gemm9<<<dim3(32, 8), dim3(512), 0, stream>>>(
      peM, b2h, b2, out);
}